// Round 14
// baseline (23210.112 us; speedup 1.0000x reference)
//
#include <hip/hip_runtime.h>
#include <hip/hip_bf16.h>

#define T_ 512
#define B_ 128
#define D_ 256
#define H_ 256
#define EPS 1e-5f

typedef __attribute__((ext_vector_type(8))) short short8;
typedef __attribute__((ext_vector_type(4))) short short4v;
typedef __attribute__((ext_vector_type(4))) float f32x4;
typedef unsigned long long ull;

// ---- weight arena: [42 slots][8 wave][8 kf][64 lane][8 e] bf16 = 2.75MB ----
// slot s: 0-11 gates (g=s>>2, half=(s>>1)&1, tile=s&1, K=512),
//         12-17 aux (a=(s-12)>>1: Cx,Wlt,Chw; tile=s&1),
//         18-41 trans (li=(s-18)/6, m=((s-18)%6)>>1, tile=s&1).
// element (slot, wv, kf, lane, e): col = wv*32 + tile*16 + (lane&15),
//   k = [half*256 +] (lane>>4)*8 + kf*32 + e
#define SLOT_SH  32768          // shorts per slot (64KB)
#define WT_TOTAL 1376256

// LDS layout (bytes)
#define L_XBF   0               // [16][256] bf16 x, XOR-swizzled       (8192)
#define L_HBF   8192            // [16][256] bf16 h, XOR-swizzled       (8192)
#define L_STATP 16384           // f32 [96 pair][8 wave] partials       (3072)
#define L_STATF 19456           // f32 [96] finals                      (384)
#define L_WB    20480           // 2 x 65536 weight ring                (131072)
#define L_END   151552

__device__ __forceinline__ short f2bf(float f) {
  unsigned u = __builtin_bit_cast(unsigned, f);
  u = (u + 0x7FFFu + ((u >> 16) & 1u)) >> 16;   // RNE
  return (short)u;
}
__device__ __forceinline__ f32x4 zero4() { f32x4 z = {0.f, 0.f, 0.f, 0.f}; return z; }
__device__ __forceinline__ f32x4 mfma16(short8 a, short8 b, f32x4 c) {
  return __builtin_amdgcn_mfma_f32_16x16x32_bf16(a, b, c, 0, 0, 0);
}

typedef __attribute__((address_space(1))) const void gvoid_t;
typedef __attribute__((address_space(3))) void lvoid_t;
__device__ __forceinline__ void gl16(const void* g, void* l) {
  // async global->LDS DMA, 16B/lane; LDS dest = wave-uniform base + lane*16
  __builtin_amdgcn_global_load_lds((gvoid_t*)g, (lvoid_t*)l, 16, 0, 0);
}

// ---------------- weight prep: f32 -> bf16, slot-major DMA layout ----------------
__global__ void prep_weights(const float* __restrict__ Wr, const float* __restrict__ Wz,
                             const float* __restrict__ Wl, const float* __restrict__ Wlt,
                             const float* __restrict__ Cx, const float* __restrict__ Chw,
                             const float* __restrict__ tWr, const float* __restrict__ tWz,
                             const float* __restrict__ tWc, short* __restrict__ wt) {
  int idx = blockIdx.x * 256 + threadIdx.x;
  if (idx >= WT_TOTAL) return;
  int slot = idx >> 15;            // /32768
  int r2   = idx & 32767;
  int e    = r2 & 7;
  int q    = r2 >> 3;              // 0..4095
  int lane = q & 63;
  int kf   = (q >> 6) & 7;
  int wv   = q >> 9;               // 0..7
  int la = lane & 15, lh = lane >> 4;
  int tile = slot & 1;
  int col = wv * 32 + tile * 16 + la;
  float v;
  if (slot < 12) {                 // gates, K=512
    int g = slot >> 2, half = (slot >> 1) & 1;
    int k = half * 256 + lh * 8 + kf * 32 + e;
    const float* W = (g == 0) ? Wr : (g == 1 ? Wz : Wl);
    v = W[k * 256 + col];
  } else if (slot < 18) {          // aux, K=256
    int a = (slot - 12) >> 1;
    int k = lh * 8 + kf * 32 + e;
    const float* W = (a == 0) ? Cx : (a == 1 ? Wlt : Chw);
    v = W[k * 256 + col];
  } else {                         // transitions, K=256
    int q3 = slot - 18;
    int li = q3 / 6, m = (q3 % 6) >> 1;
    int k = lh * 8 + kf * 32 + e;
    const float* W = (m == 0) ? tWr : (m == 1 ? tWz : tWc);
    v = W[(li * 256 + k) * 256 + col];
  }
  wt[idx] = f2bf(v);
}

// ---- zero-sync DMA-streamed kernel: 8 WGs (1/XCD) x 16 batch rows, 8 waves ----
__global__ __launch_bounds__(512, 1)
void rnn_dma(const float* __restrict__ x, const int* __restrict__ lengths,
             const float* __restrict__ gr, const float* __restrict__ br,
             const float* __restrict__ gz, const float* __restrict__ bz,
             const float* __restrict__ gl, const float* __restrict__ bl,
             const float* __restrict__ Chb,
             const float* __restrict__ tgr, const float* __restrict__ tbr,
             const float* __restrict__ tgz, const float* __restrict__ tbz,
             const float* __restrict__ tbc,
             const short* __restrict__ W, float* __restrict__ out) {

  __shared__ __align__(16) char smem[L_END];

  const int tid = threadIdx.x;
  const int w = tid >> 6, lane = tid & 63;
  const int la = lane & 15, lh = lane >> 4;
  const int amask = (la & 7) << 4;
  const int rb0 = blockIdx.x * 16;

  // preload per-lane params: cols c0 = w*32+la (tile0), c1 = c0+16 (tile1)
  const int c0 = w * 32 + la, c1 = c0 + 16;
  float pgr[2] = {gr[c0], gr[c1]}, pbr[2] = {br[c0], br[c1]};
  float pgz[2] = {gz[c0], gz[c1]}, pbz[2] = {bz[c0], bz[c1]};
  float pgl[2] = {gl[c0], gl[c1]}, pbl[2] = {bl[c0], bl[c1]};
  float pcb[2] = {Chb[c0], Chb[c1]};
  float ptg[4][2], ptbr[4][2], ptz[4][2], ptbz[4][2], ptc[4][2];
  #pragma unroll
  for (int li = 0; li < 4; ++li) {
    ptg[li][0] = tgr[li * 256 + c0]; ptg[li][1] = tgr[li * 256 + c1];
    ptbr[li][0] = tbr[li * 256 + c0]; ptbr[li][1] = tbr[li * 256 + c1];
    ptz[li][0] = tgz[li * 256 + c0]; ptz[li][1] = tgz[li * 256 + c1];
    ptbz[li][0] = tbz[li * 256 + c0]; ptbz[li][1] = tbz[li * 256 + c1];
    ptc[li][0] = tbc[li * 256 + c0]; ptc[li][1] = tbc[li * 256 + c1];
  }

  int lenr[4];
  #pragma unroll
  for (int i = 0; i < 4; ++i) lenr[i] = lengths[rb0 + lh * 4 + i];
  int maxlen = 0;
  for (int i = 0; i < 16; ++i) {
    int v = lengths[rb0 + i];
    maxlen = maxlen > v ? maxlen : v;
  }

  // zero HBF
  for (int i = tid; i < 1024; i += 512) ((short4v*)(smem + L_HBF))[i] = (short4v){0, 0, 0, 0};

  float hr[2][4];                  // h: [tile][row lh*4+i], col w*32+tile*16+la
  #pragma unroll
  for (int tl = 0; tl < 2; ++tl)
    #pragma unroll
    for (int i = 0; i < 4; ++i) hr[tl][i] = 0.f;

  int cb = 0, nslot = 0;

  auto stageNext = [&]() {         // issue DMA of slot `nslot` into buf cb^1
    const short* sp = W + (size_t)nslot * SLOT_SH;
    char* db = smem + L_WB + (cb ^ 1) * 65536 + w * 1024;
    #pragma unroll
    for (int i2 = 0; i2 < 8; ++i2)
      gl16(sp + ((size_t)i2 * 512 + tid) * 8, db + i2 * 8192);
    nslot = (nslot == 41) ? 0 : nslot + 1;
  };
  auto cslot = [&](f32x4& acc, int AB) {   // consume current slot from buf cb
    const char* bb = smem + L_WB + cb * 65536 + w * 8192 + lane * 16;
    #pragma unroll
    for (int kf = 0; kf < 8; ++kf) {
      short8 bv = *(const short8*)(bb + kf * 1024);
      short8 av = *(const short8*)(smem + AB + la * 512 + (((kf * 64) + lh * 16) ^ amask));
      acc = mfma16(av, bv, acc);
    }
  };
  auto endslot = [&]() { __syncthreads(); cb ^= 1; };  // full drain: DMA + LDS
  auto lbar = [&]() {              // LDS-only barrier (keeps DMA in flight)
    asm volatile("s_waitcnt lgkmcnt(0)" ::: "memory");
    __builtin_amdgcn_s_barrier();
  };
  auto stageX = [&](int tt) {
    const float* xs = x + ((size_t)tt * B_ + rb0 + (tid >> 5)) * D_ + (tid & 31) * 8;
    int row2 = tid >> 5;
    f32x4 a = *(const f32x4*)xs;
    f32x4 b = *(const f32x4*)(xs + 4);
    short8 s;
    s[0] = f2bf(a[0]); s[1] = f2bf(a[1]); s[2] = f2bf(a[2]); s[3] = f2bf(a[3]);
    s[4] = f2bf(b[0]); s[5] = f2bf(b[1]); s[6] = f2bf(b[2]); s[7] = f2bf(b[3]);
    *(short8*)(smem + L_XBF + row2 * 512 + (((tid & 31) * 16) ^ ((row2 & 7) << 4))) = s;
  };

  f32x4 ga[6][2];                  // gate-round accs [array][tile]
  f32x4 ta[3][2];                  // transition accs

  auto gelem = [&](int t) {
    float p1[3][4], p2[3][4];
    #pragma unroll
    for (int g = 0; g < 3; ++g)
      #pragma unroll
      for (int i = 0; i < 4; ++i) {
        float v0 = ga[g][0][i], v1 = ga[g][1][i];
        float a = v0 + v1, b = v0 * v0 + v1 * v1;
        a += __shfl_xor(a, 1); b += __shfl_xor(b, 1);
        a += __shfl_xor(a, 2); b += __shfl_xor(b, 2);
        a += __shfl_xor(a, 4); b += __shfl_xor(b, 4);
        a += __shfl_xor(a, 8); b += __shfl_xor(b, 8);
        p1[g][i] = a; p2[g][i] = b;
      }
    #pragma unroll
    for (int g = 0; g < 3; ++g)
      #pragma unroll
      for (int i = 0; i < 4; ++i) {
        int row = lh * 4 + i;
        if (la == 2 * g)
          *(float*)(smem + L_STATP + (((2 * g) * 16 + row) * 8 + w) * 4) = p1[g][i];
        if (la == 2 * g + 1)
          *(float*)(smem + L_STATP + (((2 * g + 1) * 16 + row) * 8 + w) * 4) = p2[g][i];
      }
    lbar();
    if (tid < 96) {
      f32x4 a = *(const f32x4*)(smem + L_STATP + tid * 32);
      f32x4 b = *(const f32x4*)(smem + L_STATP + tid * 32 + 16);
      f32x4 s = a + b;
      *(float*)(smem + L_STATF + tid * 4) = (s[0] + s[1]) + (s[2] + s[3]);
    }
    lbar();
    float m3[3][4], r3[3][4];
    #pragma unroll
    for (int g = 0; g < 3; ++g)
      #pragma unroll
      for (int i = 0; i < 4; ++i) {
        int row = lh * 4 + i;
        float s1 = *(const float*)(smem + L_STATF + ((2 * g) * 16 + row) * 4);
        float s2 = *(const float*)(smem + L_STATF + ((2 * g + 1) * 16 + row) * 4);
        float mm = s1 * (1.f / 256.f);
        float vv = s2 * (1.f / 256.f) - mm * mm;
        m3[g][i] = mm; r3[g][i] = rsqrtf((vv > 0.f ? vv : 0.f) + EPS);
      }
    #pragma unroll
    for (int tl = 0; tl < 2; ++tl)
      #pragma unroll
      for (int i = 0; i < 4; ++i) {
        float P0 = ga[0][tl][i], P1 = ga[1][tl][i], P2 = ga[2][tl][i];
        float P3 = ga[3][tl][i], P4 = ga[4][tl][i], P5 = ga[5][tl][i];
        float rv = 1.f / (1.f + __expf(-((P0 - m3[0][i]) * r3[0][i] * pgr[tl] + pbr[tl])));
        float zv = 1.f / (1.f + __expf(-((P1 - m3[1][i]) * r3[1][i] * pgz[tl] + pbz[tl])));
        float lv = 1.f / (1.f + __expf(-((P2 - m3[2][i]) * r3[2][i] * pgl[tl] + pbl[tl])));
        float n = tanhf(P3 + rv * (P5 + pcb[tl])) + lv * P4;
        float h = hr[tl][i];
        float hn = (t < lenr[i]) ? ((1.f - zv) * h + zv * n) : h;
        hr[tl][i] = hn;
        int row = lh * 4 + i;
        int colB = (w * 32 + tl * 16 + la) * 2;
        *(short*)(smem + L_HBF + row * 512 + (colB ^ ((row & 7) << 4))) = f2bf(hn);
      }
  };

  auto telem = [&](int t, const float (&qr)[2], const float (&qbr)[2],
                   const float (&qz)[2], const float (&qbz)[2],
                   const float (&qc)[2], bool last) {
    float p1[2][4], p2[2][4];
    #pragma unroll
    for (int g = 0; g < 2; ++g)
      #pragma unroll
      for (int i = 0; i < 4; ++i) {
        float v0 = ta[g][0][i], v1 = ta[g][1][i];
        float a = v0 + v1, b = v0 * v0 + v1 * v1;
        a += __shfl_xor(a, 1); b += __shfl_xor(b, 1);
        a += __shfl_xor(a, 2); b += __shfl_xor(b, 2);
        a += __shfl_xor(a, 4); b += __shfl_xor(b, 4);
        a += __shfl_xor(a, 8); b += __shfl_xor(b, 8);
        p1[g][i] = a; p2[g][i] = b;
      }
    #pragma unroll
    for (int g = 0; g < 2; ++g)
      #pragma unroll
      for (int i = 0; i < 4; ++i) {
        int row = lh * 4 + i;
        if (la == 2 * g)
          *(float*)(smem + L_STATP + (((2 * g) * 16 + row) * 8 + w) * 4) = p1[g][i];
        if (la == 2 * g + 1)
          *(float*)(smem + L_STATP + (((2 * g + 1) * 16 + row) * 8 + w) * 4) = p2[g][i];
      }
    lbar();
    if (tid < 64) {
      f32x4 a = *(const f32x4*)(smem + L_STATP + tid * 32);
      f32x4 b = *(const f32x4*)(smem + L_STATP + tid * 32 + 16);
      f32x4 s = a + b;
      *(float*)(smem + L_STATF + tid * 4) = (s[0] + s[1]) + (s[2] + s[3]);
    }
    lbar();
    float m2[2][4], r2[2][4];
    #pragma unroll
    for (int g = 0; g < 2; ++g)
      #pragma unroll
      for (int i = 0; i < 4; ++i) {
        int row = lh * 4 + i;
        float s1 = *(const float*)(smem + L_STATF + ((2 * g) * 16 + row) * 4);
        float s2 = *(const float*)(smem + L_STATF + ((2 * g + 1) * 16 + row) * 4);
        float mm = s1 * (1.f / 256.f);
        float vv = s2 * (1.f / 256.f) - mm * mm;
        m2[g][i] = mm; r2[g][i] = rsqrtf((vv > 0.f ? vv : 0.f) + EPS);
      }
    #pragma unroll
    for (int tl = 0; tl < 2; ++tl)
      #pragma unroll
      for (int i = 0; i < 4; ++i) {
        float P0 = ta[0][tl][i], P1 = ta[1][tl][i], P2 = ta[2][tl][i];
        float rv = 1.f / (1.f + __expf(-((P0 - m2[0][i]) * r2[0][i] * qr[tl] + qbr[tl])));
        float zv = 1.f / (1.f + __expf(-((P1 - m2[1][i]) * r2[1][i] * qz[tl] + qbz[tl])));
        float n = tanhf(rv * (P2 + qc[tl]));
        float h = hr[tl][i];
        bool act = t < lenr[i];
        float hn = act ? ((1.f - zv) * n + zv * h) : h;
        hr[tl][i] = hn;
        int row = lh * 4 + i;
        int colB = (w * 32 + tl * 16 + la) * 2;
        *(short*)(smem + L_HBF + row * 512 + (colB ^ ((row & 7) << 4))) = f2bf(hn);
        if (last) {
          out[((size_t)t * B_ + rb0 + row) * H_ + w * 32 + tl * 16 + la] = act ? hn : 0.f;
        }
      }
  };

  // ---- prologue: stage slot 0 into buf0, stage x_0, drain ----
  {
    const short* sp = W;
    char* db = smem + L_WB + w * 1024;
    #pragma unroll
    for (int i2 = 0; i2 < 8; ++i2)
      gl16(sp + ((size_t)i2 * 512 + tid) * 8, db + i2 * 8192);
    nslot = 1;
  }
  if (maxlen > 0) stageX(0);
  __syncthreads();

  #pragma unroll 1
  for (int t = 0; t < maxlen; ++t) {
    #pragma unroll
    for (int g = 0; g < 6; ++g) { ga[g][0] = zero4(); ga[g][1] = zero4(); }

    // gates: per g: x t0, x t1, h t0, h t1
    stageNext(); cslot(ga[0][0], L_XBF); endslot();
    stageNext(); cslot(ga[0][1], L_XBF); endslot();
    stageNext(); cslot(ga[0][0], L_HBF); endslot();
    stageNext(); cslot(ga[0][1], L_HBF); endslot();
    stageNext(); cslot(ga[1][0], L_XBF); endslot();
    stageNext(); cslot(ga[1][1], L_XBF); endslot();
    stageNext(); cslot(ga[1][0], L_HBF); endslot();
    stageNext(); cslot(ga[1][1], L_HBF); endslot();
    stageNext(); cslot(ga[2][0], L_XBF); endslot();
    stageNext(); cslot(ga[2][1], L_XBF); endslot();
    stageNext(); cslot(ga[2][0], L_HBF); endslot();
    stageNext(); cslot(ga[2][1], L_HBF); endslot();
    // aux: Cx, Wlt (A=XBF), Chw (A=HBF)
    stageNext(); cslot(ga[3][0], L_XBF); endslot();
    stageNext(); cslot(ga[3][1], L_XBF); endslot();
    stageNext(); cslot(ga[4][0], L_XBF); endslot();
    stageNext(); cslot(ga[4][1], L_XBF); endslot();
    stageNext(); cslot(ga[5][0], L_HBF); endslot();
    stageNext(); cslot(ga[5][1], L_HBF);
    gelem(t);                      // overlaps in-flight DMA of next slot
    endslot();

    // transition layers
    #pragma unroll 1
    for (int li = 0; li < 4; ++li) {
      #pragma unroll
      for (int m = 0; m < 3; ++m) { ta[m][0] = zero4(); ta[m][1] = zero4(); }
      stageNext(); cslot(ta[0][0], L_HBF); endslot();
      stageNext(); cslot(ta[0][1], L_HBF); endslot();
      stageNext(); cslot(ta[1][0], L_HBF); endslot();
      stageNext(); cslot(ta[1][1], L_HBF); endslot();
      stageNext(); cslot(ta[2][0], L_HBF); endslot();
      stageNext(); cslot(ta[2][1], L_HBF);
      switch (li) {
        case 0: telem(t, ptg[0], ptbr[0], ptz[0], ptbz[0], ptc[0], false); break;
        case 1: telem(t, ptg[1], ptbr[1], ptz[1], ptbz[1], ptc[1], false); break;
        case 2: telem(t, ptg[2], ptbr[2], ptz[2], ptbz[2], ptc[2], false); break;
        default:
          telem(t, ptg[3], ptbr[3], ptz[3], ptbz[3], ptc[3], true);
          if (t + 1 < maxlen) stageX(t + 1);
          break;
      }
      endslot();
    }
  }

  // tail: zero outputs past this WG's longest sequence
  for (int t2 = maxlen; t2 < T_; ++t2) {
    float* o = out + ((size_t)t2 * B_ + rb0 + (tid >> 5)) * H_ + (tid & 31) * 8;
    *(f32x4*)o = zero4();
    *(f32x4*)(o + 4) = zero4();
  }
}

extern "C" void kernel_launch(void* const* d_in, const int* in_sizes, int n_in,
                              void* d_out, int out_size, void* d_ws, size_t ws_size,
                              hipStream_t stream) {
  const float* x    = (const float*)d_in[0];
  const int* lengths = (const int*)d_in[1];
  const float* Wr   = (const float*)d_in[2];
  const float* gr   = (const float*)d_in[3];
  const float* br   = (const float*)d_in[4];
  const float* Wz   = (const float*)d_in[5];
  const float* gz   = (const float*)d_in[6];
  const float* bz   = (const float*)d_in[7];
  const float* Wl   = (const float*)d_in[8];
  const float* gl   = (const float*)d_in[9];
  const float* bl   = (const float*)d_in[10];
  const float* Wlt  = (const float*)d_in[11];
  const float* Cx   = (const float*)d_in[12];
  const float* Chw  = (const float*)d_in[13];
  const float* Chb  = (const float*)d_in[14];
  const float* tWr  = (const float*)d_in[15];
  const float* tgr  = (const float*)d_in[16];
  const float* tbr  = (const float*)d_in[17];
  const float* tWz  = (const float*)d_in[18];
  const float* tgz  = (const float*)d_in[19];
  const float* tbz  = (const float*)d_in[20];
  const float* tWc  = (const float*)d_in[21];
  const float* tbc  = (const float*)d_in[22];

  short* wt = (short*)d_ws;

  hipLaunchKernelGGL(prep_weights, dim3((WT_TOTAL + 255) / 256), dim3(256), 0, stream,
                     Wr, Wz, Wl, Wlt, Cx, Chw, tWr, tWz, tWc, wt);
  hipLaunchKernelGGL(rnn_dma, dim3(8), dim3(512), 0, stream,
                     x, lengths, gr, br, gz, bz, gl, bl, Chb,
                     tgr, tbr, tgz, tbz, tbc, wt, (float*)d_out);
}